// Round 12
// baseline (185.163 us; speedup 1.0000x reference)
//
#include <hip/hip_runtime.h>
#include <hip/hip_bf16.h>

#define B_ 2
#define T_ 2048
#define C_ 1024
#define H_ 16
#define D_ 64

typedef __attribute__((ext_vector_type(8))) short bf16x8;
typedef __attribute__((ext_vector_type(4))) float f32x4;

static __device__ __forceinline__ float bf2f(unsigned short u) {
  union { unsigned int i; float f; } c;
  c.i = ((unsigned int)u) << 16;
  return c.f;
}
static __device__ __forceinline__ unsigned short f2bf(float f) {
  union { float f; unsigned int i; } c;
  c.f = f;
  unsigned int x = c.i;
  return (unsigned short)((x + 0x7fffu + ((x >> 16) & 1u)) >> 16);  // RNE
}

// async global->LDS, 16B per lane; LDS dest = (wave-uniform base) + lane*16
static __device__ __forceinline__ void gl_lds16(const void* g, void* s) {
  __builtin_amdgcn_global_load_lds(
      (const __attribute__((address_space(1))) void*)g,
      (__attribute__((address_space(3))) void*)s, 16, 0, 0);
}

// ---------------------------------------------------------------------------
__global__ __launch_bounds__(256) void fill_kernel_f32(float* __restrict__ out,
                                                       int n, float v) {
  int i = blockIdx.x * 256 + threadIdx.x;
  if (i < n) out[i] = v;
}

// ---------------------------------------------------------------------------
// Fused prep:
//   z=0: w_attn [1024][3072] -> waT [3072][1024] bf16   (96x32 tiles)
//   z=1: w_proj [1024][1024] -> wpT [1024][1024] bf16
//   z=2: x fp32 -> xb bf16, 8 elems/thread
// ---------------------------------------------------------------------------
__global__ __launch_bounds__(256) void prep_kernel(
    const float* __restrict__ w_attn, const float* __restrict__ w_proj,
    const float* __restrict__ x,
    unsigned short* __restrict__ waT, unsigned short* __restrict__ wpT,
    unsigned short* __restrict__ xb) {
  __shared__ float tile[32][33];
  const int z = blockIdx.z;
  if (z == 2) {
    const int id = blockIdx.y * 96 + blockIdx.x;
    if (id >= 2048) return;
    int i = (id * 256 + threadIdx.x) * 8;
    float4 f0 = *(const float4*)(x + i);
    float4 f1 = *(const float4*)(x + i + 4);
    union { unsigned short u[8]; uint4 v; } p;
    p.u[0] = f2bf(f0.x); p.u[1] = f2bf(f0.y); p.u[2] = f2bf(f0.z); p.u[3] = f2bf(f0.w);
    p.u[4] = f2bf(f1.x); p.u[5] = f2bf(f1.y); p.u[6] = f2bf(f1.z); p.u[7] = f2bf(f1.w);
    *(uint4*)(xb + i) = p.v;
    return;
  }
  const float* W;
  unsigned short* WT;
  int Kd, Nd;
  if (z == 0) { W = w_attn; WT = waT; Kd = 1024; Nd = 3072; }
  else {
    if (blockIdx.x >= 32) return;
    W = w_proj; WT = wpT; Kd = 1024; Nd = 1024;
  }
  const int n0 = blockIdx.x * 32, k0 = blockIdx.y * 32;
  const int tx = threadIdx.x & 31, ty = threadIdx.x >> 5;  // ty 0..7
#pragma unroll
  for (int i = 0; i < 4; ++i)
    tile[ty + i * 8][tx] = W[(size_t)(k0 + ty + i * 8) * Nd + n0 + tx];
  __syncthreads();
#pragma unroll
  for (int i = 0; i < 4; ++i)
    WT[(size_t)(n0 + ty + i * 8) * Kd + k0 + tx] = f2bf(tile[tx][ty + i * 8]);
}

// ---------------------------------------------------------------------------
// MFMA GEMM: C = A(bf16)[M,K] @ BT(bf16)[N,K]^T + bias.
// 128x128 tile, BK=64, 4 waves, m97 staging (verified).
// OUT_PLANES=1:
//   q/k planes: RoPE fused (HW trig, v10-verified) -> LDS -> 8x uint4 stores.
//     v15: q scale = 0.125 * log2(e) -- scores arrive pre-multiplied by
//     log2e so flash uses a bare v_exp (exp2) with no per-element mul.
//   v plane (pl==2): direct transposed store to vT (verified v13).
// OUT_PLANES=0: fp32 out via two 64-row LDS passes, 8x float4 stores.
// ---------------------------------------------------------------------------
template <int OUT_PLANES>
__global__ __launch_bounds__(256) void mfma_gemm(
    const unsigned short* __restrict__ A,
    const unsigned short* __restrict__ BT,
    const float* __restrict__ bias,
    unsigned short* __restrict__ qP, unsigned short* __restrict__ kP,
    unsigned short* __restrict__ vT, float* __restrict__ Fout,
    int N, int K) {
  __shared__ unsigned short S[128 * 128];   // loop: As|Bs; epilogue: staging
  unsigned short* As = S;
  unsigned short* Bs = S + 128 * 64;

  const int tid = threadIdx.x;
  const int w = tid >> 6, lane = tid & 63;
  const int lo = lane & 15, g = lane >> 4;
  const int wm = (w >> 1) * 64, wn = (w & 1) * 64;
  const int m0 = blockIdx.y * 128, n0 = blockIdx.x * 128;

  const int lr8 = lane >> 3;           // row within the 8-row instr span

  const f32x4 zero4 = {0.f, 0.f, 0.f, 0.f};
  f32x4 acc[4][4] = {{zero4, zero4, zero4, zero4}, {zero4, zero4, zero4, zero4},
                     {zero4, zero4, zero4, zero4}, {zero4, zero4, zero4, zero4}};

  for (int k0 = 0; k0 < K; k0 += 64) {
    __syncthreads();  // previous iteration's frag readers done
#pragma unroll
    for (int it = 0; it < 4; ++it) {
      const int base_row = w * 32 + it * 8;       // wave-uniform
      const int r = base_row + lr8;               // this lane's row
      const int j = (lane & 7) ^ (r & 7);         // global chunk for LDS chunk lane&7
      gl_lds16(A + (size_t)(m0 + r) * K + k0 + j * 8, &As[base_row * 64]);
      gl_lds16(BT + (size_t)(n0 + r) * K + k0 + j * 8, &Bs[base_row * 64]);
    }
    __syncthreads();  // drains vmcnt -> staging visible

#pragma unroll
    for (int kk = 0; kk < 2; ++kk) {
      bf16x8 af[4], bfr[4];
#pragma unroll
      for (int i = 0; i < 4; ++i) {
        int ra = wm + i * 16 + lo;
        int rb = wn + i * 16 + lo;
        af[i]  = *(const bf16x8*)&As[ra * 64 + ((g + kk * 4) ^ (ra & 7)) * 8];
        bfr[i] = *(const bf16x8*)&Bs[rb * 64 + ((g + kk * 4) ^ (rb & 7)) * 8];
      }
#pragma unroll
      for (int i = 0; i < 4; ++i)
#pragma unroll
        for (int j = 0; j < 4; ++j)
          acc[i][j] = __builtin_amdgcn_mfma_f32_16x16x32_bf16(af[i], bfr[j],
                                                              acc[i][j], 0, 0, 0);
    }
  }

  float bv[4];
#pragma unroll
  for (int j = 0; j < 4; ++j) bv[j] = bias[n0 + wn + j * 16 + lo];

  if (OUT_PLANES) {
    const int pl = n0 >> 10;
    if (pl == 2) {
      // ---- v plane: direct transposed store to vT (verified v13)
      const int b = m0 >> 11;                  // uniform per block
      const int t0base = m0 & 2047;
      const int colbase = (n0 & 1023) + wn + lo;
#pragma unroll
      for (int i = 0; i < 4; ++i) {
        const int tt = t0base + wm + i * 16 + g * 4;
#pragma unroll
        for (int j = 0; j < 4; ++j) {
          const int col = colbase + j * 16;
          unsigned int u0 = (unsigned int)f2bf(acc[i][j][0] + bv[j]) |
                            ((unsigned int)f2bf(acc[i][j][1] + bv[j]) << 16);
          unsigned int u1 = (unsigned int)f2bf(acc[i][j][2] + bv[j]) |
                            ((unsigned int)f2bf(acc[i][j][3] + bv[j]) << 16);
          uint2 pw; pw.x = u0; pw.y = u1;
          *(uint2*)(vT + ((size_t)(b * 1024 + col)) * 2048 + tt) = pw;
        }
      }
    } else {
      __syncthreads();  // all frag readers done; S reusable
      // ---- q/k planes: fused RoPE (HW trig in revolutions; v10-verified).
      // v15: q pre-scaled by 0.125*log2(e) so flash softmax is a bare exp2.
      const float scale = (pl == 0) ? 0.18033688011112042f : 1.0f;
      const float invA = exp2f((float)(-2 * lo) * (13.287712379549449f / 64.0f)) *
                         0.15915494309189535f;
      const float invB = exp2f((float)(-2 * (lo + 16)) * (13.287712379549449f / 64.0f)) *
                         0.15915494309189535f;
      const int c0 = wn + lo;
#pragma unroll
      for (int i = 0; i < 4; ++i)
#pragma unroll
        for (int r = 0; r < 4; ++r) {
          const int row = wm + i * 16 + g * 4 + r;
          const float t = (float)((m0 + row) & (T_ - 1));
          float ra = t * invA; ra -= floorf(ra);    // [0,1) revolutions
          float rb = t * invB; rb -= floorf(rb);
          const float sA = __builtin_amdgcn_sinf(ra);
          const float cA = __builtin_amdgcn_cosf(ra);
          const float sB = __builtin_amdgcn_sinf(rb);
          const float cB = __builtin_amdgcn_cosf(rb);
          const float q1A = acc[i][0][r] + bv[0];
          const float q2A = acc[i][2][r] + bv[2];
          const float q1B = acc[i][1][r] + bv[1];
          const float q2B = acc[i][3][r] + bv[3];
          S[row * 128 + c0]      = f2bf((q1A * cA - q2A * sA) * scale);
          S[row * 128 + c0 + 32] = f2bf((q2A * cA + q1A * sA) * scale);
          S[row * 128 + c0 + 16] = f2bf((q1B * cB - q2B * sB) * scale);
          S[row * 128 + c0 + 48] = f2bf((q2B * cB + q1B * sB) * scale);
        }
      __syncthreads();
      // ---- vectorized store: 8x uint4/thread, coalesced
      unsigned short* P = (pl == 0) ? qP : kP;
      const int pcol0 = n0 & 1023;
#pragma unroll
      for (int it2 = 0; it2 < 8; ++it2) {
        const int p = it2 * 256 + tid;          // uint4 index 0..2047
        const int lrow = p >> 4;                // 128 rows x 16 uint4
        const int lcol = (p & 15) * 8;
        uint4 v4 = *(const uint4*)&S[lrow * 128 + lcol];
        *(uint4*)(P + (size_t)(m0 + lrow) * 1024 + pcol0 + lcol) = v4;
      }
    }
  } else {
    // ---- fp32 out via two 64-row LDS passes (S as float[64][128])
    float* Sf = (float*)S;
#pragma unroll
    for (int hh = 0; hh < 2; ++hh) {
      __syncthreads();
      if ((w >> 1) == hh) {
#pragma unroll
        for (int i = 0; i < 4; ++i)
#pragma unroll
          for (int r = 0; r < 4; ++r) {
            const int lrow = i * 16 + g * 4 + r;
#pragma unroll
            for (int j = 0; j < 4; ++j)
              Sf[lrow * 128 + wn + j * 16 + lo] = acc[i][j][r] + bv[j];
          }
      }
      __syncthreads();
#pragma unroll
      for (int it2 = 0; it2 < 8; ++it2) {
        const int p = it2 * 256 + tid;        // float4 index 0..2047
        const int lrow = p >> 5;              // 64 rows x 32 float4
        const int lcol = (p & 31) * 4;
        float4 v4 = *(const float4*)&Sf[lrow * 128 + lcol];
        *(float4*)(Fout + (size_t)(m0 + hh * 64 + lrow) * N + n0 + lcol) = v4;
      }
    }
  }
}

// ---------------------------------------------------------------------------
// flash K/V staging: gl_lds16 with pre-swizzled global source (GEMM idiom,
// PMC-verified conflict-free). Tile = 64 rows x 64 bf16 (128B); wave w covers
// rows w*16+it*8; lane lands at LDS chunk lane&7, fetching global chunk
// (lane&7)^(r&7). LDS dest is wave-uniform base + lane*16 (HW rule).
// ---------------------------------------------------------------------------
static __device__ __forceinline__ void flash_stage(
    const unsigned short* kbase, const unsigned short* vbase,
    unsigned short* Kbuf, unsigned short* Vbuf,
    int kt, int w, int lr8, int lc8) {
#pragma unroll
  for (int it = 0; it < 2; ++it) {
    const int base = w * 16 + it * 8;        // wave-uniform
    const int r = base + lr8;                // this lane's row
    const int j = lc8 ^ (r & 7);             // global chunk for LDS chunk lc8
    gl_lds16(kbase + (size_t)(kt * 64 + r) * 1024 + j * 8, Kbuf + base * 64);
    gl_lds16(vbase + (size_t)r * 2048 + kt * 64 + j * 8, Vbuf + base * 64);
  }
}

// ---------------------------------------------------------------------------
// flash v15 = v14 structure (gl_lds staging, 1 barrier/iter, XCD-chunked
// grid, paired tiles, swapped QK^T, setprio) with the VALU softmax halved:
//  * scores arrive pre-multiplied by log2e (folded into q's GEMM scale) ->
//    p = v_exp (exp2) directly, no per-element mul.
//  * P-pack via v_cvt_pk_bf16_f32 (HW RNE, identical bits to manual f2bf):
//    2 asm ops replace ~18 VALU ops per ct.
// Per-iter core VALU ~108 -> ~36 ops. v14 PMC: VALUBusy 47%, MfmaUtil 14%,
// HBM 6% -> VALU-throughput-bound; this attacks exactly that pipe.
// ---------------------------------------------------------------------------
__global__ __launch_bounds__(256) void flash_v15(
    unsigned short* __restrict__ qP,
    const unsigned short* __restrict__ kP,
    const unsigned short* __restrict__ vT) {
  const int cid = blockIdx.x;            // 0..511
  const int xcd = cid & 7;
  const int k6 = cid >> 3;               // 0..63
  const int bh = xcd * 4 + (k6 >> 4);    // 4 bh per XCD
  const int bx = k6 & 15;                // 0..15
  const int b = bh >> 4, h = bh & 15;
  const int tid = threadIdx.x;
  const int w = tid >> 6, lane = tid & 63;
  const int lo = lane & 15, g = lane >> 4;
  const int lr8 = lane >> 3, lc8 = lane & 7;

  __shared__ unsigned short Ks[2][64 * 64];   // [buf][key*64 + d-chunked]
  __shared__ unsigned short VTs[2][64 * 64];  // [buf][d*64 + key-chunked]
  __shared__ unsigned short Ps[64][72];       // [q][key], padded

  const f32x4 zero4 = {0.f, 0.f, 0.f, 0.f};

  const unsigned short* kbase = kP + (size_t)b * T_ * 1024 + h * 64;
  const unsigned short* vbase = vT + (size_t)bh * 64 * 2048;

#pragma unroll
  for (int half = 0; half < 2; ++half) {
    const int qt = half ? (31 - bx) : bx;
    const int rowq0 = b * T_ + qt * 64;

    // Q fragments for this wave's 16 q-rows (B-operand of swapped QK).
    const unsigned short* qrow = qP + (size_t)(rowq0 + w * 16 + lo) * 1024 + h * 64;
    bf16x8 aq0 = *(const bf16x8*)(qrow + g * 8);
    bf16x8 aq1 = *(const bf16x8*)(qrow + 32 + g * 8);

    f32x4 oacc[4] = {zero4, zero4, zero4, zero4};  // O[q=w*16+g*4+r][d=c2*16+lo]
    float lsum = 0.f;                              // denom partial, q = w*16+lo

    // prologue: tile 0 -> buf 0 (prior half's last barrier protects reuse)
    flash_stage(kbase, vbase, Ks[0], VTs[0], 0, w, lr8, lc8);
    asm volatile("s_waitcnt vmcnt(0)" ::: "memory");
    __builtin_amdgcn_sched_barrier(0);
    __builtin_amdgcn_s_barrier();

    for (int kt = 0; kt <= qt; ++kt) {
      const int buf = kt & 1;
      if (kt < qt)
        flash_stage(kbase, vbase, Ks[buf ^ 1], VTs[buf ^ 1], kt + 1, w, lr8, lc8);

      // ---- swapped QK^T: sacc[ct][r] = S^T[k=ct*16+g*4+r][q=w*16+lo]
      f32x4 sacc[4] = {zero4, zero4, zero4, zero4};
      __builtin_amdgcn_s_setprio(1);
#pragma unroll
      for (int ct = 0; ct < 4; ++ct) {
        const int r = ct * 16 + lo;
        bf16x8 bk0 = *(const bf16x8*)&Ks[buf][r * 64 + ((g)     ^ (r & 7)) * 8];
        bf16x8 bk1 = *(const bf16x8*)&Ks[buf][r * 64 + ((g + 4) ^ (r & 7)) * 8];
        sacc[ct] = __builtin_amdgcn_mfma_f32_16x16x32_bf16(bk0, aq0, sacc[ct], 0, 0, 0);
        sacc[ct] = __builtin_amdgcn_mfma_f32_16x16x32_bf16(bk1, aq1, sacc[ct], 0, 0, 0);
      }
      __builtin_amdgcn_s_setprio(0);

      // ---- causal mask (diagonal tile only): local k > local q -> -inf
      if (kt == qt) {
#pragma unroll
        for (int ct = 0; ct < 4; ++ct)
#pragma unroll
          for (int r = 0; r < 4; ++r)
            if (ct * 16 + g * 4 + r > w * 16 + lo) sacc[ct][r] = -1e30f;
      }

      // ---- softmax numerator: bare exp2 (log2e pre-folded into q) +
      //      v_cvt_pk_bf16_f32 pack (HW RNE) -> one b64 LDS write per ct
#pragma unroll
      for (int ct = 0; ct < 4; ++ct) {
        float p0 = __builtin_amdgcn_exp2f(sacc[ct][0]);
        float p1 = __builtin_amdgcn_exp2f(sacc[ct][1]);
        float p2 = __builtin_amdgcn_exp2f(sacc[ct][2]);
        float p3 = __builtin_amdgcn_exp2f(sacc[ct][3]);
        lsum += (p0 + p1) + (p2 + p3);
        unsigned int u0, u1;
        asm("v_cvt_pk_bf16_f32 %0, %1, %2" : "=v"(u0) : "v"(p0), "v"(p1));
        asm("v_cvt_pk_bf16_f32 %0, %1, %2" : "=v"(u1) : "v"(p2), "v"(p3));
        uint2 pw; pw.x = u0; pw.y = u1;
        *(uint2*)&Ps[w * 16 + lo][ct * 16 + g * 4] = pw;
      }

      // ---- PV (same-wave Ps write->read, in-order DS pipe)
      bf16x8 ap0 = *(const bf16x8*)&Ps[w * 16 + lo][g * 8];
      bf16x8 ap1 = *(const bf16x8*)&Ps[w * 16 + lo][32 + g * 8];
      __builtin_amdgcn_s_setprio(1);
#pragma unroll
      for (int c2 = 0; c2 < 4; ++c2) {
        const int r = c2 * 16 + lo;
        bf16x8 bv0 = *(const bf16x8*)&VTs[buf][r * 64 + ((g)     ^ (r & 7)) * 8];
        bf16x8 bv1 = *(const bf16x8*)&VTs[buf][r * 64 + ((g + 4) ^ (r & 7)) * 8];
        oacc[c2] = __builtin_amdgcn_mfma_f32_16x16x32_bf16(ap0, bv0, oacc[c2], 0, 0, 0);
        oacc[c2] = __builtin_amdgcn_mfma_f32_16x16x32_bf16(ap1, bv1, oacc[c2], 0, 0, 0);
      }
      __builtin_amdgcn_s_setprio(0);

      // ---- end of phase: prefetch landed + all waves' reads of buf done
      asm volatile("s_waitcnt vmcnt(0)" ::: "memory");
      __builtin_amdgcn_sched_barrier(0);
      __builtin_amdgcn_s_barrier();
    }

    // ---- denominator: reduce over g (lanes with same lo), then per-r pickup
    lsum += __shfl_xor(lsum, 16);
    lsum += __shfl_xor(lsum, 32);   // lanes {lo,lo+16,lo+32,lo+48}: full denom

#pragma unroll
    for (int r = 0; r < 4; ++r) {
      float inv_r = 1.0f / __shfl(lsum, g * 4 + r);  // lane s holds q=w*16+s
      unsigned short* dst = qP + (size_t)(rowq0 + w * 16 + g * 4 + r) * 1024 + h * 64 + lo;
#pragma unroll
      for (int c2 = 0; c2 < 4; ++c2)
        dst[c2 * 16] = f2bf(oacc[c2][r] * inv_r);
    }
    // last iter's barrier protects LDS reuse by next half's prologue stage
  }
}

// ---------------------------------------------------------------------------
extern "C" void kernel_launch(void* const* d_in, const int* in_sizes, int n_in,
                              void* d_out, int out_size, void* d_ws, size_t ws_size,
                              hipStream_t stream) {
  const float *x = nullptr, *w_attn = nullptr, *b_attn = nullptr,
              *w_proj = nullptr, *b_proj = nullptr;
  for (int i = 0; i < n_in; ++i) {
    switch (in_sizes[i]) {
      case B_ * T_ * C_:  x      = (const float*)d_in[i]; break;
      case C_ * 3 * C_:   w_attn = (const float*)d_in[i]; break;
      case 3 * C_:        b_attn = (const float*)d_in[i]; break;
      case C_ * C_:       w_proj = (const float*)d_in[i]; break;
      case C_:            b_proj = (const float*)d_in[i]; break;
      default: break;
    }
  }
  float* out = (float*)d_out;
  const int nblk = (out_size + 255) / 256;

  if (!x || !w_attn || !b_attn || !w_proj || !b_proj) {
    fill_kernel_f32<<<nblk, 256, 0, stream>>>(out, out_size, 100.0f);  // SENTINEL
    return;
  }
  // ws >= 48 MB proven (rounds 10/11 fast path). Sentinel otherwise.
  if (ws_size < (size_t)48 * 1024 * 1024) {
    fill_kernel_f32<<<nblk, 256, 0, stream>>>(out, out_size, 50.0f);   // SENTINEL
    return;
  }

  // layout: q|k planes (16 MB) | vP slot (8, unused) | vT (8) | xb (8) |
  //         waT (6) | wpT (2) = 48 MB
  unsigned short* qP  = (unsigned short*)d_ws;
  unsigned short* kP  = qP + (size_t)(B_ * T_) * 1024;
  unsigned short* vP  = kP + (size_t)(B_ * T_) * 1024;   // unused (kept for layout)
  unsigned short* vT  = vP + (size_t)(B_ * T_) * 1024;
  unsigned short* xb  = vT + (size_t)(B_ * T_) * 1024;
  unsigned short* waT = xb + (size_t)(B_ * T_) * C_;
  unsigned short* wpT = waT + (size_t)C_ * 3 * C_;
  (void)vP;

  // 0) fused prep: weight transposes + x conversion
  prep_kernel<<<dim3(96, 32, 3), 256, 0, stream>>>(w_attn, w_proj, x, waT, wpT, xb);
  // 1) qkv = xb @ w_attn + b_attn; RoPE fused (q scaled by 0.125*log2e),
  //    V transposed-stored to vT
  mfma_gemm<1><<<dim3((3 * C_) / 128, (B_ * T_) / 128), 256, 0, stream>>>(
      xb, waT, b_attn, qP, kP, vT, nullptr, 3 * C_, C_);
  // 2) causal flash attention v15 (bare exp2 + cvt_pk softmax)
  flash_v15<<<dim3(512), 256, 0, stream>>>(qP, kP, vT);
  // 3) out = y @ w_proj + b_proj (fp32 out, vectorized epilogue)
  mfma_gemm<0><<<dim3(C_ / 128, (B_ * T_) / 128), 256, 0, stream>>>(
      qP, wpT, b_proj, nullptr, nullptr, nullptr, out, C_, C_);
}